// Round 4
// baseline (979.552 us; speedup 1.0000x reference)
//
#include <hip/hip_runtime.h>
#include <hip/hip_fp16.h>

// ---------------------------------------------------------------------------
// Bidirectional 5-layer LSTM decoder, B=1024, H=32, T=200, feedback y->x.
// Round 18 = r17 (8 waves, AGPR-direct MFMA, q-major units) with the 5
// per-ts __syncthreads REPLACED by point-to-point LDS flag sync:
//   - regions double-buffered by ts parity (2 x 5 x 16 x 36 words): WAR
//     hazards span 2 ts -> only RAW gates needed.
//   - per-region u32 counter; producer wave bumps it (lane0 ds_add) after
//     its h-store; consumer spin-reads until flag[L] >= 8*(ts+1).
//   - recurrent-MFMA hoist: layer l+1's W_hh*h(t-1) MFMA runs in segment l
//     (operand nb2 is prefetched there), carried as acc_next across the
//     poll -> post-poll chain is 2 MFMAs, and waves do matrix work while
//     stragglers store.
// RAW/WAR audit (no barriers):
//   * consumer of region[p][L] polls flag[L] >= 8(ts+1); producer bumped
//     AFTER its ds_write (same-wave DS in-order) -> data visible.
//   * prefetch LOADXQ(l+1) reads region[p^1][l+1] = h(ts-1); its writer at
//     ts+1 is gated on flag[l] >= 8(ts+2), one full round later -> no WAR.
//   * SEG4 prefetch LOADXP(0) (h0(ts)): poll3 success => all waves past
//     SEG3@ts => past SEG0@ts => region[p][0] complete. No extra gate.
//   * SEG0 needs no gate: operands are y (local) + acc_next (register).
//   * Y reads region[p][4] after poll4; next write to that buffer is
//     SEG4@(ts+2), gated 2 rounds later.
// Fences: sched_barrier(0)+"memory" after each poll (stop LICM/hoist of the
// data ds_reads) and before each bump (keep store->bump order).
// ---------------------------------------------------------------------------

#define T_STEPS 200
#define BATCH 1024

#define BIAS_OFF_B  231424            // 1280 floats [l*2+d][u][g]
#define BLIN_OFF_B  236544            // 3 floats
#define START_OFF_B 236556            // 3 floats

typedef _Float16 half8 __attribute__((ext_vector_type(8)));
typedef float f32x4 __attribute__((ext_vector_type(4)));
typedef unsigned u32x4 __attribute__((ext_vector_type(4)));

__global__ __launch_bounds__(256) void prep_kernel(
    const float* __restrict__ Wih0, const float* __restrict__ Whh0,
    const float* __restrict__ bih0, const float* __restrict__ bhh0,
    const float* __restrict__ Wih,  const float* __restrict__ Whh,
    const float* __restrict__ bih,  const float* __restrict__ bhh,
    const float* __restrict__ Wlin, const float* __restrict__ blin,
    const float* __restrict__ stok, char* __restrict__ ws)
{
    int i = blockIdx.x * 256 + threadIdx.x;
    _Float16* Wo = (_Float16*)ws;
    float* biasf  = (float*)(ws + BIAS_OFF_B);
    float* blinf  = (float*)(ws + BLIN_OFF_B);
    float* startf = (float*)(ws + START_OFF_B);

    if (i < 16384) {                       // layer-0 A-frags
        int fid = i >> 9, r = i & 511;
        int lane = r >> 3, j = r & 7, q = lane >> 4, m = lane & 15;
        int kk = fid & 1, t = (fid >> 1) & 3, half = (fid >> 3) & 1, d = fid >> 4;
        int k = kk * 32 + q * 8 + j;
        int unit = half * 16 + (m >> 2) * 4 + t;   // q-major, t-minor
        int gr = (m & 3) * 32 + unit;      // torch gate order i,f,g,o
        float v = 0.f;
        if (k < 3)       v = Wih0[(d * 128 + gr) * 3 + k];
        else if (k >= 32) v = Whh0[(d * 128 + gr) * 32 + (k - 32)];
        Wo[i] = (_Float16)v;
    } else if (i < 114688) {               // layers 1-4 A-frags
        int e = i - 16384;
        int fid = e >> 9, r = e & 511;
        int lane = r >> 3, j = r & 7, q = lane >> 4, m = lane & 15;
        int kk = fid % 3, t = (fid / 3) & 3, half = (fid / 12) & 1;
        int d = (fid / 24) & 1, l1 = fid / 48;
        int k = kk * 32 + q * 8 + j;
        int unit = half * 16 + (m >> 2) * 4 + t;   // q-major, t-minor
        int gr = (m & 3) * 32 + unit;
        float v;
        if (k < 64) v = Wih[((l1 * 2 + d) * 128 + gr) * 64 + k];
        else        v = Whh[((l1 * 2 + d) * 128 + gr) * 32 + (k - 64)];
        Wo[i] = (_Float16)v;
    } else if (i < 115712) {               // Wlin A-frags (M rows 0..2 used)
        int e = i - 114688;
        int fid = e >> 9, r = e & 511;
        int lane = r >> 3, j = r & 7, q = lane >> 4, m = lane & 15;
        int k = fid * 32 + q * 8 + j;
        Wo[i] = (_Float16)((m < 3) ? Wlin[m * 64 + k] : 0.f);
    } else if (i < 115712 + 1280) {        // fused biases [l*2+d][u][g]
        int b = i - 115712;
        int ld = b / 128, rem = b % 128;
        int u = rem / 4, g = rem % 4;
        int gr = g * 32 + u;
        float v;
        if (ld < 2) v = bih0[ld * 128 + gr] + bhh0[ld * 128 + gr];
        else        v = bih[(ld - 2) * 128 + gr] + bhh[(ld - 2) * 128 + gr];
        biasf[b] = v;
    } else if (i < 115712 + 1280 + 3) {
        blinf[i - (115712 + 1280)] = blin[i - (115712 + 1280)];
    } else if (i < 115712 + 1280 + 6) {
        startf[i - (115712 + 1280 + 3)] = stok[i - (115712 + 1280 + 3)];
    }
}

__device__ __forceinline__ float sigm(float x)  { return 1.f / (1.f + __expf(-x)); }
__device__ __forceinline__ float tanhx(float x) { return 2.f * sigm(2.f * x) - 1.f; }
__device__ __forceinline__ unsigned short f2h_bits(float x) {
    return __builtin_bit_cast(unsigned short, (_Float16)x);
}

// Park a 16B fragment into a contiguous AGPR quad (r17-proven).
__device__ __forceinline__ half8 park_frag(uint4 v) {
    u32x4 t; t[0] = v.x; t[1] = v.y; t[2] = v.z; t[3] = v.w;
    u32x4 r;
    __asm__("" : "=a"(r) : "0"(t));
    return __builtin_bit_cast(half8, r);
}

#define MFMA(A, B, C) __builtin_amdgcn_mfma_f32_16x16x32_f16((A), (B), (C), 0, 0, 0)

// per-wave frag slots (30 frags = 120 AGPR)
#define SL0(tt, kk)    ((tt) * 2 + (kk))                       // 0..3
#define SL(l, tt, kk)  (4 + (((l) - 1) * 2 + (tt)) * 3 + (kk)) // 4..27
#define SWL(kk)        (28 + (kk))                             // 28,29

// spin until *f >= target; fence so data ds_reads can't hoist above.
__device__ __forceinline__ void poll_ge(const unsigned* f, unsigned target) {
    const volatile unsigned* vf = (const volatile unsigned*)f;
    while (*vf < target) { }
    __asm__ volatile("" ::: "memory");
    __builtin_amdgcn_sched_barrier(0);
}
// bump region flag after the h-store (fence keeps store->bump order).
__device__ __forceinline__ void flag_bump(unsigned* f, int lane) {
    __asm__ volatile("" ::: "memory");
    __builtin_amdgcn_sched_barrier(0);
    if (lane == 0) atomicAdd(f, 1u);
}

__global__ __launch_bounds__(512, 2) void lstm_kernel(
    const char* __restrict__ ws,
    const float* __restrict__ h0,
    const float* __restrict__ c0,
    float* __restrict__ out)
{
    const int tid  = threadIdx.x;
    const int w    = tid >> 6;
    const int d    = w & 1;           // direction
    const int half = (w >> 1) & 1;    // unit half
    const int tp   = w >> 2;          // t-pair (t = 2*tp + tt)
    const int lane = tid & 63;
    const int q    = lane >> 4;       // quad
    const int n    = lane & 15;       // batch row within block
    const int row  = blockIdx.x * 16 + n;

    // parity-doubled regions: [2][5][16 rows][36 words] + 5 flags (+pad)
    __shared__ unsigned zb[5768];
    unsigned* zf = zb + 5760;

    const uint4* gw4 = (const uint4*)ws;
    const float* biasf  = (const float*)(ws + BIAS_OFF_B);
    const float* blinf  = (const float*)(ws + BLIN_OFF_B);
    const float* startf = (const float*)(ws + START_OFF_B);

    for (int i = tid; i < 5768; i += 512) zb[i] = 0;
    __syncthreads();

    // ---- park this wave's A-fragments in AGPRs (30 frags = 120 AGPR) ----
    half8 afr[30];
#pragma unroll
    for (int tt = 0; tt < 2; tt++)
#pragma unroll
        for (int kk = 0; kk < 2; kk++) {
            int t = 2 * tp + tt;
            uint4 v = gw4[(((d * 2 + half) * 4 + t) * 2 + kk) * 64 + lane];
            afr[SL0(tt, kk)] = park_frag(v);
        }
#pragma unroll
    for (int l1 = 0; l1 < 4; l1++)
#pragma unroll
        for (int tt = 0; tt < 2; tt++)
#pragma unroll
            for (int kk = 0; kk < 3; kk++) {
                int t = 2 * tp + tt;
                int fid = (((l1 * 2 + d) * 2 + half) * 4 + t) * 3 + kk;
                uint4 v = gw4[2048 + fid * 64 + lane];
                afr[SL(l1 + 1, tt, kk)] = park_frag(v);
            }
#pragma unroll
    for (int kk = 0; kk < 2; kk++) {
        uint4 v = gw4[14336 + kk * 64 + lane];
        afr[SWL(kk)] = park_frag(v);
    }

    // ---- biases (VGPRs), c-state, h-init into PARITY-1 regions ----------
    f32x4 bias[5][2];
    float cs[5][2];
    {
        unsigned short* zh1 = (unsigned short*)(zb + 2880);   // parity 1
#pragma unroll
        for (int l = 0; l < 5; l++)
#pragma unroll
            for (int tt = 0; tt < 2; tt++) {
                int unit = half * 16 + q * 4 + (2 * tp + tt); // q-major remap
                bias[l][tt] = *(const f32x4*)(biasf + ((l * 2 + d) * 32 + unit) * 4);
                int idx = ((2 * l + d) * BATCH + row) * 32 + unit;
                cs[l][tt] = c0[idx];
                zh1[l * 1152 + n * 72 + d * 32 + unit] = f2h_bits(h0[idx]);
            }
    }
    const float bl0 = blinf[0], bl1 = blinf[1], bl2 = blinf[2];
    float y0 = startf[0], y1 = startf[1], y2 = startf[2];
    __syncthreads();

#define LOADAT(BASE, L, DD) \
    __builtin_bit_cast(half8, *(const uint4*)&(BASE)[(L) * 576 + n * 36 + (DD) * 16 + q * 4])
#define STPACK(ZH, L, P) \
    *(unsigned*)((ZH) + (L) * 1152 + n * 72 + d * 32 + half * 16 + q * 4 + 2 * tp) = (P);
#define ACT_STORE(ZH, L, A0, A1, CSL)                                   \
    {                                                                    \
        f32x4 a2[2] = {(A0), (A1)};                                      \
        unsigned short hb[2];                                            \
        _Pragma("unroll")                                                \
        for (int tt = 0; tt < 2; tt++) {                                 \
            float ii = sigm(a2[tt][0]), ff = sigm(a2[tt][1]);            \
            float gg = tanhx(a2[tt][2]), oo = sigm(a2[tt][3]);           \
            (CSL)[tt] = ff * (CSL)[tt] + ii * gg;                        \
            hb[tt] = f2h_bits(oo * tanhx((CSL)[tt]));                    \
        }                                                                \
        STPACK(ZH, L, (unsigned)hb[0] | ((unsigned)hb[1] << 16));        \
    }

    // acc_next pipeline: layer-(next)'s recurrent MFMA result, crosses polls
    f32x4 accnA, accnB;
    {
        half8 bh0i = LOADAT(zb + 2880, 0, d);     // parity-1 region 0 = h0(-1)
        accnA = MFMA(afr[SL0(0, 1)], bh0i, bias[0][0]);
        accnB = MFMA(afr[SL0(1, 1)], bh0i, bias[0][1]);
    }
    half8 by;
    by[0] = (q == 0) ? (_Float16)y0 : (_Float16)0.f;
    by[1] = (q == 0) ? (_Float16)y1 : (_Float16)0.f;
    by[2] = (q == 0) ? (_Float16)y2 : (_Float16)0.f;
    by[3] = (_Float16)0.f; by[4] = (_Float16)0.f;
    by[5] = (_Float16)0.f; by[6] = (_Float16)0.f; by[7] = (_Float16)0.f;

    for (int ts = 0; ts < T_STEPS; ts++) {
        const int p = ts & 1;
        unsigned* zbp = zb + p * 2880;            // current-parity regions
        unsigned* zbq = zb + (p ^ 1) * 2880;      // previous-parity regions
        unsigned short* zhp = (unsigned short*)zbp;
        const unsigned tgt = 8u * (unsigned)(ts + 1);

        // ---------- SEG0: layer 0 (no gate: y local, accn in regs) -------
        {
            f32x4 acc0 = MFMA(afr[SL0(0, 0)], by, accnA);
            f32x4 acc1 = MFMA(afr[SL0(1, 0)], by, accnB);
            half8 nb2 = LOADAT(zbq, 1, d);        // h1(ts-1), no WAR (audit)
            accnA = MFMA(afr[SL(1, 0, 2)], nb2, bias[1][0]);
            accnB = MFMA(afr[SL(1, 1, 2)], nb2, bias[1][1]);
            ACT_STORE(zhp, 0, acc0, acc1, cs[0]);
            flag_bump(&zf[0], lane);
        }

        // ---------- SEG 1..3 ---------------------------------------------
#pragma unroll
        for (int l = 1; l <= 3; l++) {
            poll_ge(&zf[l - 1], tgt);
            half8 b0 = LOADAT(zbp, l - 1, 0);
            half8 b1 = LOADAT(zbp, l - 1, 1);
            half8 nb2 = LOADAT(zbq, l + 1, d);    // h_{l+1}(ts-1)
            f32x4 acc0 = MFMA(afr[SL(l, 0, 0)], b0, accnA);
            f32x4 acc1 = MFMA(afr[SL(l, 1, 0)], b0, accnB);
            acc0 = MFMA(afr[SL(l, 0, 1)], b1, acc0);
            acc1 = MFMA(afr[SL(l, 1, 1)], b1, acc1);
            accnA = MFMA(afr[SL(l + 1, 0, 2)], nb2, bias[l + 1][0]);
            accnB = MFMA(afr[SL(l + 1, 1, 2)], nb2, bias[l + 1][1]);
            ACT_STORE(zhp, l, acc0, acc1, cs[l]);
            flag_bump(&zf[l], lane);
        }

        // ---------- SEG4 --------------------------------------------------
        {
            poll_ge(&zf[3], tgt);
            half8 b0 = LOADAT(zbp, 3, 0);
            half8 b1 = LOADAT(zbp, 3, 1);
            half8 nbh0 = LOADAT(zbp, 0, d);       // h0(ts); gated by poll3
            f32x4 acc0 = MFMA(afr[SL(4, 0, 0)], b0, accnA);
            f32x4 acc1 = MFMA(afr[SL(4, 1, 0)], b0, accnB);
            acc0 = MFMA(afr[SL(4, 0, 1)], b1, acc0);
            acc1 = MFMA(afr[SL(4, 1, 1)], b1, acc1);
            accnA = MFMA(afr[SL0(0, 1)], nbh0, bias[0][0]);   // L0 rec, ts+1
            accnB = MFMA(afr[SL0(1, 1)], nbh0, bias[0][1]);
            ACT_STORE(zhp, 4, acc0, acc1, cs[4]);
            flag_bump(&zf[4], lane);
        }

        // ---------- Y: all waves redundant -------------------------------
        {
            poll_ge(&zf[4], tgt);
            half8 c0f = LOADAT(zbp, 4, 0);
            half8 c1f = LOADAT(zbp, 4, 1);
            f32x4 acc = (f32x4){0.f, 0.f, 0.f, 0.f};
            acc = MFMA(afr[SWL(0)], c0f, acc);
            acc = MFMA(afr[SWL(1)], c1f, acc);
            y0 = tanhx(acc[0] + bl0);     // valid on q==0 lanes
            y1 = tanhx(acc[1] + bl1);
            y2 = tanhx(acc[2] + bl2);
            if (w == 0 && q == 0) {
                float* op = out + (ts * BATCH + row) * 3;
                op[0] = y0; op[1] = y1; op[2] = y2;
            }
            by[0] = (q == 0) ? (_Float16)y0 : (_Float16)0.f;
            by[1] = (q == 0) ? (_Float16)y1 : (_Float16)0.f;
            by[2] = (q == 0) ? (_Float16)y2 : (_Float16)0.f;
        }
    }
#undef LOADAT
#undef STPACK
#undef ACT_STORE
}

extern "C" void kernel_launch(void* const* d_in, const int* in_sizes, int n_in,
                              void* d_out, int out_size, void* d_ws, size_t ws_size,
                              hipStream_t stream)
{
    const float* h0   = (const float*)d_in[0];
    const float* c0   = (const float*)d_in[1];
    const float* stok = (const float*)d_in[2];
    const float* Wih0 = (const float*)d_in[3];
    const float* Whh0 = (const float*)d_in[4];
    const float* bih0 = (const float*)d_in[5];
    const float* bhh0 = (const float*)d_in[6];
    const float* Wih  = (const float*)d_in[7];
    const float* Whh  = (const float*)d_in[8];
    const float* bih  = (const float*)d_in[9];
    const float* bhh  = (const float*)d_in[10];
    const float* Wlin = (const float*)d_in[11];
    const float* blin = (const float*)d_in[12];

    prep_kernel<<<458, 256, 0, stream>>>(Wih0, Whh0, bih0, bhh0, Wih, Whh,
                                         bih, bhh, Wlin, blin, stok, (char*)d_ws);
    lstm_kernel<<<64, 512, 0, stream>>>((const char*)d_ws, h0, c0, (float*)d_out);
}

// Round 5
// 885.846 us; speedup vs baseline: 1.1058x; 1.1058x over previous
//
#include <hip/hip_runtime.h>
#include <hip/hip_fp16.h>

// ---------------------------------------------------------------------------
// Bidirectional 5-layer LSTM decoder, B=1024, H=32, T=200, feedback y->x.
// Round 19 = r17 (8 waves 2/SIMD, barriers, AGPR-direct MFMA) + chain cuts:
//   - parity-doubled h regions (2x5x16x36 words) + recurrent-MFMA hoist:
//     layer l+1's W_hh*h(t-1) MFMA issues in segment l (operand prefetched
//     from previous-parity region, safe under barrier ordering), carried as
//     accnA/B across the barrier -> post-barrier chain is 2 MFMAs, not 3.
//     (r18 proved the dataflow; r18's regression was the POLLS, not this --
//     barriers kept, 5 per ts.)
//   - L0 input VALU-ized: W_ih0 has K=3, so the by-build + 2 by-MFMAs are
//     replaced by 12 f32 fma/lane/tt from a 24-entry register table loaded
//     pre-loop directly from the original Wih0 global (no ws change).
//   - Wlin rows REPLICATED in prep (A[m] = Wlin[m&3]) so the Y-MFMA yields
//     y0..y2 in acc[0..2] on ALL lanes (not just q==0) -- makes the L0
//     VALU-ization shuffle-free. Same MFMA cost.
// r18 lesson: s_barrier < LDS flag polling. r15 lesson: keep 2 waves/SIMD.
// Race audit (barriers): consumer of region[p][l] runs after the barrier
// following its producer segment. Prefetch nb2 reads region[p^1][l+1]
// (= h(ts-1)); its next writer is SEG_{l+1}@(ts+1), many barriers later.
// SEG4's nbh0 reads region[p][0] (h0(ts)), produced pre-B1, read post-B4.
// Y reads region[p][4] post-B5; next writer SEG4@(ts+2). No WAR/RAW holes.
// ---------------------------------------------------------------------------

#define T_STEPS 200
#define BATCH 1024

#define BIAS_OFF_B  231424            // 1280 floats [l*2+d][u][g]
#define BLIN_OFF_B  236544            // 3 floats
#define START_OFF_B 236556            // 3 floats

typedef _Float16 half8 __attribute__((ext_vector_type(8)));
typedef float f32x4 __attribute__((ext_vector_type(4)));
typedef unsigned u32x4 __attribute__((ext_vector_type(4)));

__global__ __launch_bounds__(256) void prep_kernel(
    const float* __restrict__ Wih0, const float* __restrict__ Whh0,
    const float* __restrict__ bih0, const float* __restrict__ bhh0,
    const float* __restrict__ Wih,  const float* __restrict__ Whh,
    const float* __restrict__ bih,  const float* __restrict__ bhh,
    const float* __restrict__ Wlin, const float* __restrict__ blin,
    const float* __restrict__ stok, char* __restrict__ ws)
{
    int i = blockIdx.x * 256 + threadIdx.x;
    _Float16* Wo = (_Float16*)ws;
    float* biasf  = (float*)(ws + BIAS_OFF_B);
    float* blinf  = (float*)(ws + BLIN_OFF_B);
    float* startf = (float*)(ws + START_OFF_B);

    if (i < 16384) {                       // layer-0 A-frags
        int fid = i >> 9, r = i & 511;
        int lane = r >> 3, j = r & 7, q = lane >> 4, m = lane & 15;
        int kk = fid & 1, t = (fid >> 1) & 3, half = (fid >> 3) & 1, d = fid >> 4;
        int k = kk * 32 + q * 8 + j;
        int unit = half * 16 + (m >> 2) * 4 + t;   // q-major, t-minor
        int gr = (m & 3) * 32 + unit;      // torch gate order i,f,g,o
        float v = 0.f;
        if (k < 3)       v = Wih0[(d * 128 + gr) * 3 + k];
        else if (k >= 32) v = Whh0[(d * 128 + gr) * 32 + (k - 32)];
        Wo[i] = (_Float16)v;
    } else if (i < 114688) {               // layers 1-4 A-frags
        int e = i - 16384;
        int fid = e >> 9, r = e & 511;
        int lane = r >> 3, j = r & 7, q = lane >> 4, m = lane & 15;
        int kk = fid % 3, t = (fid / 3) & 3, half = (fid / 12) & 1;
        int d = (fid / 24) & 1, l1 = fid / 48;
        int k = kk * 32 + q * 8 + j;
        int unit = half * 16 + (m >> 2) * 4 + t;   // q-major, t-minor
        int gr = (m & 3) * 32 + unit;
        float v;
        if (k < 64) v = Wih[((l1 * 2 + d) * 128 + gr) * 64 + k];
        else        v = Whh[((l1 * 2 + d) * 128 + gr) * 32 + (k - 64)];
        Wo[i] = (_Float16)v;
    } else if (i < 115712) {               // Wlin A-frags, rows REPLICATED %4
        int e = i - 114688;
        int fid = e >> 9, r = e & 511;
        int lane = r >> 3, j = r & 7, q = lane >> 4, m = lane & 15;
        int k = fid * 32 + q * 8 + j;
        int mr = m & 3;                    // row m holds Wlin[m&3] (row3 = 0)
        Wo[i] = (_Float16)((mr < 3) ? Wlin[mr * 64 + k] : 0.f);
    } else if (i < 115712 + 1280) {        // fused biases [l*2+d][u][g]
        int b = i - 115712;
        int ld = b / 128, rem = b % 128;
        int u = rem / 4, g = rem % 4;
        int gr = g * 32 + u;
        float v;
        if (ld < 2) v = bih0[ld * 128 + gr] + bhh0[ld * 128 + gr];
        else        v = bih[(ld - 2) * 128 + gr] + bhh[(ld - 2) * 128 + gr];
        biasf[b] = v;
    } else if (i < 115712 + 1280 + 3) {
        blinf[i - (115712 + 1280)] = blin[i - (115712 + 1280)];
    } else if (i < 115712 + 1280 + 6) {
        startf[i - (115712 + 1280 + 3)] = stok[i - (115712 + 1280 + 3)];
    }
}

__device__ __forceinline__ float sigm(float x)  { return 1.f / (1.f + __expf(-x)); }
__device__ __forceinline__ float tanhx(float x) { return 2.f * sigm(2.f * x) - 1.f; }
__device__ __forceinline__ unsigned short f2h_bits(float x) {
    return __builtin_bit_cast(unsigned short, (_Float16)x);
}

// Park a 16B fragment into a contiguous AGPR quad (r17-proven).
__device__ __forceinline__ half8 park_frag(uint4 v) {
    u32x4 t; t[0] = v.x; t[1] = v.y; t[2] = v.z; t[3] = v.w;
    u32x4 r;
    __asm__("" : "=a"(r) : "0"(t));
    return __builtin_bit_cast(half8, r);
}

#define MFMA(A, B, C) __builtin_amdgcn_mfma_f32_16x16x32_f16((A), (B), (C), 0, 0, 0)

// per-wave frag slots (28 frags = 112 AGPR)
#define SL0R(tt)       (tt)                                     // 0..1  (Whh0)
#define SL(l, tt, kk)  (2 + (((l) - 1) * 2 + (tt)) * 3 + (kk))  // 2..25
#define SWL(kk)        (26 + (kk))                              // 26,27

__global__ __launch_bounds__(512, 2) void lstm_kernel(
    const char* __restrict__ ws,
    const float* __restrict__ h0,
    const float* __restrict__ c0,
    const float* __restrict__ Wih0g,
    float* __restrict__ out)
{
    const int tid  = threadIdx.x;
    const int w    = tid >> 6;
    const int d    = w & 1;           // direction
    const int half = (w >> 1) & 1;    // unit half
    const int tp   = w >> 2;          // t-pair (t = 2*tp + tt)
    const int lane = tid & 63;
    const int q    = lane >> 4;       // quad
    const int n    = lane & 15;       // batch row within block
    const int row  = blockIdx.x * 16 + n;

    // parity-doubled regions: [2][5][16 rows][36 words]
    __shared__ unsigned zb[5760];

    const uint4* gw4 = (const uint4*)ws;
    const float* biasf  = (const float*)(ws + BIAS_OFF_B);
    const float* blinf  = (const float*)(ws + BLIN_OFF_B);
    const float* startf = (const float*)(ws + START_OFF_B);

    for (int i = tid; i < 5760; i += 512) zb[i] = 0;
    __syncthreads();

    // ---- park this wave's A-fragments in AGPRs (28 frags = 112 AGPR) ----
    half8 afr[28];
#pragma unroll
    for (int tt = 0; tt < 2; tt++) {      // L0: only the Whh0 (kk=1) frag
        int t = 2 * tp + tt;
        uint4 v = gw4[((((d * 2 + half) * 4 + t) * 2) + 1) * 64 + lane];
        afr[SL0R(tt)] = park_frag(v);
    }
#pragma unroll
    for (int l1 = 0; l1 < 4; l1++)
#pragma unroll
        for (int tt = 0; tt < 2; tt++)
#pragma unroll
            for (int kk = 0; kk < 3; kk++) {
                int t = 2 * tp + tt;
                int fid = (((l1 * 2 + d) * 2 + half) * 4 + t) * 3 + kk;
                uint4 v = gw4[2048 + fid * 64 + lane];
                afr[SL(l1 + 1, tt, kk)] = park_frag(v);
            }
#pragma unroll
    for (int kk = 0; kk < 2; kk++) {
        uint4 v = gw4[14336 + kk * 64 + lane];
        afr[SWL(kk)] = park_frag(v);
    }

    // ---- L0 input-weight columns (K=3) in registers: Wc[tt][g*3+k] ------
    float WcA[12], WcB[12];
    {
        int uA = half * 16 + q * 4 + 2 * tp;
#pragma unroll
        for (int g = 0; g < 4; g++)
#pragma unroll
            for (int k = 0; k < 3; k++) {
                WcA[g * 3 + k] = Wih0g[(d * 128 + g * 32 + uA) * 3 + k];
                WcB[g * 3 + k] = Wih0g[(d * 128 + g * 32 + uA + 1) * 3 + k];
            }
    }

    // ---- biases (VGPRs), c-state, h-init into PARITY-1 regions ----------
    f32x4 bias[5][2];
    float cs[5][2];
    {
        unsigned short* zh1 = (unsigned short*)(zb + 2880);   // parity 1
#pragma unroll
        for (int l = 0; l < 5; l++)
#pragma unroll
            for (int tt = 0; tt < 2; tt++) {
                int unit = half * 16 + q * 4 + (2 * tp + tt); // q-major remap
                bias[l][tt] = *(const f32x4*)(biasf + ((l * 2 + d) * 32 + unit) * 4);
                int idx = ((2 * l + d) * BATCH + row) * 32 + unit;
                cs[l][tt] = c0[idx];
                zh1[l * 1152 + n * 72 + d * 32 + unit] = f2h_bits(h0[idx]);
            }
    }
    const float bl0 = blinf[0], bl1 = blinf[1], bl2 = blinf[2];
    float y0 = startf[0], y1 = startf[1], y2 = startf[2];
    __syncthreads();

#define LOADAT(BASE, L, DD) \
    __builtin_bit_cast(half8, *(const uint4*)&(BASE)[(L) * 576 + n * 36 + (DD) * 16 + q * 4])
#define STPACK(ZH, L, P) \
    *(unsigned*)((ZH) + (L) * 1152 + n * 72 + d * 32 + half * 16 + q * 4 + 2 * tp) = (P);
#define ACT_STORE(ZH, L, A0, A1, CSL)                                   \
    {                                                                    \
        f32x4 a2[2] = {(A0), (A1)};                                      \
        unsigned short hb[2];                                            \
        _Pragma("unroll")                                                \
        for (int tt = 0; tt < 2; tt++) {                                 \
            float ii = sigm(a2[tt][0]), ff = sigm(a2[tt][1]);            \
            float gg = tanhx(a2[tt][2]), oo = sigm(a2[tt][3]);           \
            (CSL)[tt] = ff * (CSL)[tt] + ii * gg;                        \
            hb[tt] = f2h_bits(oo * tanhx((CSL)[tt]));                    \
        }                                                                \
        STPACK(ZH, L, (unsigned)hb[0] | ((unsigned)hb[1] << 16));        \
    }

    // accn pipeline: next-layer recurrent MFMA result, crosses barriers
    f32x4 accnA, accnB;
    {
        half8 bh0i = LOADAT(zb + 2880, 0, d);     // parity-1 region 0 = h(-1)
        accnA = MFMA(afr[SL0R(0)], bh0i, bias[0][0]);
        accnB = MFMA(afr[SL0R(1)], bh0i, bias[0][1]);
    }

    for (int ts = 0; ts < T_STEPS; ts++) {
        const int p = ts & 1;
        unsigned* zbp = zb + p * 2880;            // current-parity regions
        unsigned* zbq = zb + (p ^ 1) * 2880;      // previous-parity regions
        unsigned short* zhp = (unsigned short*)zbp;

        // ---------- SEG0: layer 0 (no pre-barrier; y + accn in regs) -----
        {
            half8 nb2 = LOADAT(zbq, 1, d);        // h1(ts-1): prefetch early
            f32x4 acc0 = accnA, acc1 = accnB;
#pragma unroll
            for (int g = 0; g < 4; g++) {         // W_ih0 (K=3) on the VALU
                acc0[g] = __builtin_fmaf(WcA[g * 3 + 0], y0,
                          __builtin_fmaf(WcA[g * 3 + 1], y1,
                          __builtin_fmaf(WcA[g * 3 + 2], y2, acc0[g])));
                acc1[g] = __builtin_fmaf(WcB[g * 3 + 0], y0,
                          __builtin_fmaf(WcB[g * 3 + 1], y1,
                          __builtin_fmaf(WcB[g * 3 + 2], y2, acc1[g])));
            }
            accnA = MFMA(afr[SL(1, 0, 2)], nb2, bias[1][0]);   // L1 recurrent
            accnB = MFMA(afr[SL(1, 1, 2)], nb2, bias[1][1]);
            ACT_STORE(zhp, 0, acc0, acc1, cs[0]);
            __syncthreads();                                   // B1
        }

        // ---------- SEG 1..3 ---------------------------------------------
#pragma unroll
        for (int l = 1; l <= 3; l++) {
            half8 b0 = LOADAT(zbp, l - 1, 0);
            half8 b1 = LOADAT(zbp, l - 1, 1);
            half8 nb2 = LOADAT(zbq, l + 1, d);    // h_{l+1}(ts-1)
            f32x4 acc0 = MFMA(afr[SL(l, 0, 0)], b0, accnA);
            f32x4 acc1 = MFMA(afr[SL(l, 1, 0)], b0, accnB);
            acc0 = MFMA(afr[SL(l, 0, 1)], b1, acc0);
            acc1 = MFMA(afr[SL(l, 1, 1)], b1, acc1);
            accnA = MFMA(afr[SL(l + 1, 0, 2)], nb2, bias[l + 1][0]);
            accnB = MFMA(afr[SL(l + 1, 1, 2)], nb2, bias[l + 1][1]);
            ACT_STORE(zhp, l, acc0, acc1, cs[l]);
            __syncthreads();                                   // B2..B4
        }

        // ---------- SEG4 --------------------------------------------------
        {
            half8 b0 = LOADAT(zbp, 3, 0);
            half8 b1 = LOADAT(zbp, 3, 1);
            half8 nbh0 = LOADAT(zbp, 0, d);       // h0(ts), produced pre-B1
            f32x4 acc0 = MFMA(afr[SL(4, 0, 0)], b0, accnA);
            f32x4 acc1 = MFMA(afr[SL(4, 1, 0)], b0, accnB);
            acc0 = MFMA(afr[SL(4, 0, 1)], b1, acc0);
            acc1 = MFMA(afr[SL(4, 1, 1)], b1, acc1);
            accnA = MFMA(afr[SL0R(0)], nbh0, bias[0][0]);      // L0 rec, ts+1
            accnB = MFMA(afr[SL0R(1)], nbh0, bias[0][1]);
            ACT_STORE(zhp, 4, acc0, acc1, cs[4]);
            __syncthreads();                                   // B5
        }

        // ---------- Y: all waves; replicated Wlin -> y on ALL lanes ------
        {
            half8 c0f = LOADAT(zbp, 4, 0);
            half8 c1f = LOADAT(zbp, 4, 1);
            f32x4 acc = (f32x4){0.f, 0.f, 0.f, 0.f};
            acc = MFMA(afr[SWL(0)], c0f, acc);
            acc = MFMA(afr[SWL(1)], c1f, acc);
            y0 = tanhx(acc[0] + bl0);             // valid on every lane now
            y1 = tanhx(acc[1] + bl1);
            y2 = tanhx(acc[2] + bl2);
            if (w == 0 && q == 0) {
                float* op = out + (ts * BATCH + row) * 3;
                op[0] = y0; op[1] = y1; op[2] = y2;
            }
        }
        // no barrier: Y reads region[p][4]; next write to it is SEG4@(ts+2).
    }
#undef LOADAT
#undef STPACK
#undef ACT_STORE
}

extern "C" void kernel_launch(void* const* d_in, const int* in_sizes, int n_in,
                              void* d_out, int out_size, void* d_ws, size_t ws_size,
                              hipStream_t stream)
{
    const float* h0   = (const float*)d_in[0];
    const float* c0   = (const float*)d_in[1];
    const float* stok = (const float*)d_in[2];
    const float* Wih0 = (const float*)d_in[3];
    const float* Whh0 = (const float*)d_in[4];
    const float* bih0 = (const float*)d_in[5];
    const float* bhh0 = (const float*)d_in[6];
    const float* Wih  = (const float*)d_in[7];
    const float* Whh  = (const float*)d_in[8];
    const float* bih  = (const float*)d_in[9];
    const float* bhh  = (const float*)d_in[10];
    const float* Wlin = (const float*)d_in[11];
    const float* blin = (const float*)d_in[12];

    prep_kernel<<<458, 256, 0, stream>>>(Wih0, Whh0, bih0, bhh0, Wih, Whh,
                                         bih, bhh, Wlin, blin, stok, (char*)d_ws);
    lstm_kernel<<<64, 512, 0, stream>>>((const char*)d_ws, h0, c0, Wih0,
                                        (float*)d_out);
}

// Round 6
// 645.080 us; speedup vs baseline: 1.5185x; 1.3732x over previous
//
#include <hip/hip_runtime.h>
#include <hip/hip_fp16.h>

// ---------------------------------------------------------------------------
// Bidirectional 5-layer LSTM decoder, B=1024, H=32, T=200, feedback y->x.
// Round 20 = r19 (8 waves 2/SIMD, 5 barriers/ts, parity regions, recurrent
// hoist, L0 VALU-ized, replicated Wlin) + activation/MFMA chain cuts:
//   - sigm uses raw v_rcp_f32 (__builtin_amdgcn_rcpf): without -ffast-math,
//     "1.f/x" was expanding to the exact-div sequence (~5 ops + ~20 cyc
//     latency) at EVERY activation site (~50/wave/ts).
//   - tanh via Pade(7,6) with input clamp +-4 (abs err <= 7e-4, well under
//     f16 rounding): 1 trans (rcp) instead of 2 (exp+div) per tanh; used at
//     gg, tanh(c) and Y's 3 tanh -> ~23 exps removed per wave per ts and
//     one exp latency off each segment's dependent chain.
//   - split-K MFMA: acc = MFMA(A0,b0,accn); accB = MFMA(A1,b1,0);
//     acc += accB. The two MFMAs issue independently (latency overlap)
//     instead of C-chained -> one MFMA latency removed per segment and Y.
// r18 lesson: s_barrier < LDS polling. r15: keep 2 waves/SIMD.
// Race audit identical to r19 (barrier-ordered; parity regions give WAR
// slack; SEG4 reads region[p][0] produced pre-B1; Y reads region[p][4]
// post-B5, next writer SEG4@(ts+2)).
// ---------------------------------------------------------------------------

#define T_STEPS 200
#define BATCH 1024

#define BIAS_OFF_B  231424            // 1280 floats [l*2+d][u][g]
#define BLIN_OFF_B  236544            // 3 floats
#define START_OFF_B 236556            // 3 floats

typedef _Float16 half8 __attribute__((ext_vector_type(8)));
typedef float f32x4 __attribute__((ext_vector_type(4)));
typedef unsigned u32x4 __attribute__((ext_vector_type(4)));

__global__ __launch_bounds__(256) void prep_kernel(
    const float* __restrict__ Wih0, const float* __restrict__ Whh0,
    const float* __restrict__ bih0, const float* __restrict__ bhh0,
    const float* __restrict__ Wih,  const float* __restrict__ Whh,
    const float* __restrict__ bih,  const float* __restrict__ bhh,
    const float* __restrict__ Wlin, const float* __restrict__ blin,
    const float* __restrict__ stok, char* __restrict__ ws)
{
    int i = blockIdx.x * 256 + threadIdx.x;
    _Float16* Wo = (_Float16*)ws;
    float* biasf  = (float*)(ws + BIAS_OFF_B);
    float* blinf  = (float*)(ws + BLIN_OFF_B);
    float* startf = (float*)(ws + START_OFF_B);

    if (i < 16384) {                       // layer-0 A-frags
        int fid = i >> 9, r = i & 511;
        int lane = r >> 3, j = r & 7, q = lane >> 4, m = lane & 15;
        int kk = fid & 1, t = (fid >> 1) & 3, half = (fid >> 3) & 1, d = fid >> 4;
        int k = kk * 32 + q * 8 + j;
        int unit = half * 16 + (m >> 2) * 4 + t;   // q-major, t-minor
        int gr = (m & 3) * 32 + unit;      // torch gate order i,f,g,o
        float v = 0.f;
        if (k < 3)       v = Wih0[(d * 128 + gr) * 3 + k];
        else if (k >= 32) v = Whh0[(d * 128 + gr) * 32 + (k - 32)];
        Wo[i] = (_Float16)v;
    } else if (i < 114688) {               // layers 1-4 A-frags
        int e = i - 16384;
        int fid = e >> 9, r = e & 511;
        int lane = r >> 3, j = r & 7, q = lane >> 4, m = lane & 15;
        int kk = fid % 3, t = (fid / 3) & 3, half = (fid / 12) & 1;
        int d = (fid / 24) & 1, l1 = fid / 48;
        int k = kk * 32 + q * 8 + j;
        int unit = half * 16 + (m >> 2) * 4 + t;   // q-major, t-minor
        int gr = (m & 3) * 32 + unit;
        float v;
        if (k < 64) v = Wih[((l1 * 2 + d) * 128 + gr) * 64 + k];
        else        v = Whh[((l1 * 2 + d) * 128 + gr) * 32 + (k - 64)];
        Wo[i] = (_Float16)v;
    } else if (i < 115712) {               // Wlin A-frags, rows REPLICATED %4
        int e = i - 114688;
        int fid = e >> 9, r = e & 511;
        int lane = r >> 3, j = r & 7, q = lane >> 4, m = lane & 15;
        int k = fid * 32 + q * 8 + j;
        int mr = m & 3;                    // row m holds Wlin[m&3] (row3 = 0)
        Wo[i] = (_Float16)((mr < 3) ? Wlin[mr * 64 + k] : 0.f);
    } else if (i < 115712 + 1280) {        // fused biases [l*2+d][u][g]
        int b = i - 115712;
        int ld = b / 128, rem = b % 128;
        int u = rem / 4, g = rem % 4;
        int gr = g * 32 + u;
        float v;
        if (ld < 2) v = bih0[ld * 128 + gr] + bhh0[ld * 128 + gr];
        else        v = bih[(ld - 2) * 128 + gr] + bhh[(ld - 2) * 128 + gr];
        biasf[b] = v;
    } else if (i < 115712 + 1280 + 3) {
        blinf[i - (115712 + 1280)] = blin[i - (115712 + 1280)];
    } else if (i < 115712 + 1280 + 6) {
        startf[i - (115712 + 1280 + 3)] = stok[i - (115712 + 1280 + 3)];
    }
}

// fast sigmoid: exp2-based exp + RAW v_rcp_f32 (no exact-div expansion)
__device__ __forceinline__ float sigm(float x) {
    return __builtin_amdgcn_rcpf(1.f + __expf(-x));
}
// tanh via Pade(7,6), input clamped to +-4 (abs err <= ~7e-4):
// tanh(x) ~ x(135135 + 17325u + 378u^2 + u^3) /
//            (135135 + 62370u + 3150u^2 + 28u^3),  u = x^2
__device__ __forceinline__ float tanhx(float x) {
    float xc = fminf(fmaxf(x, -4.0f), 4.0f);
    float u  = xc * xc;
    float p  = __builtin_fmaf(__builtin_fmaf(u + 378.0f, u, 17325.0f), u, 135135.0f);
    float qd = __builtin_fmaf(__builtin_fmaf(__builtin_fmaf(u, 28.0f, 3150.0f), u, 62370.0f), u, 135135.0f);
    return xc * p * __builtin_amdgcn_rcpf(qd);
}
__device__ __forceinline__ unsigned short f2h_bits(float x) {
    return __builtin_bit_cast(unsigned short, (_Float16)x);
}

// Park a 16B fragment into a contiguous AGPR quad (r17-proven).
__device__ __forceinline__ half8 park_frag(uint4 v) {
    u32x4 t; t[0] = v.x; t[1] = v.y; t[2] = v.z; t[3] = v.w;
    u32x4 r;
    __asm__("" : "=a"(r) : "0"(t));
    return __builtin_bit_cast(half8, r);
}

#define MFMA(A, B, C) __builtin_amdgcn_mfma_f32_16x16x32_f16((A), (B), (C), 0, 0, 0)

// per-wave frag slots (28 frags = 112 AGPR)
#define SL0R(tt)       (tt)                                     // 0..1  (Whh0)
#define SL(l, tt, kk)  (2 + (((l) - 1) * 2 + (tt)) * 3 + (kk))  // 2..25
#define SWL(kk)        (26 + (kk))                              // 26,27

__global__ __launch_bounds__(512, 2) void lstm_kernel(
    const char* __restrict__ ws,
    const float* __restrict__ h0,
    const float* __restrict__ c0,
    const float* __restrict__ Wih0g,
    float* __restrict__ out)
{
    const int tid  = threadIdx.x;
    const int w    = tid >> 6;
    const int d    = w & 1;           // direction
    const int half = (w >> 1) & 1;    // unit half
    const int tp   = w >> 2;          // t-pair (t = 2*tp + tt)
    const int lane = tid & 63;
    const int q    = lane >> 4;       // quad
    const int n    = lane & 15;       // batch row within block
    const int row  = blockIdx.x * 16 + n;

    // parity-doubled regions: [2][5][16 rows][36 words]
    __shared__ unsigned zb[5760];

    const uint4* gw4 = (const uint4*)ws;
    const float* biasf  = (const float*)(ws + BIAS_OFF_B);
    const float* blinf  = (const float*)(ws + BLIN_OFF_B);
    const float* startf = (const float*)(ws + START_OFF_B);

    for (int i = tid; i < 5760; i += 512) zb[i] = 0;
    __syncthreads();

    // ---- park this wave's A-fragments in AGPRs (28 frags = 112 AGPR) ----
    half8 afr[28];
#pragma unroll
    for (int tt = 0; tt < 2; tt++) {      // L0: only the Whh0 (kk=1) frag
        int t = 2 * tp + tt;
        uint4 v = gw4[((((d * 2 + half) * 4 + t) * 2) + 1) * 64 + lane];
        afr[SL0R(tt)] = park_frag(v);
    }
#pragma unroll
    for (int l1 = 0; l1 < 4; l1++)
#pragma unroll
        for (int tt = 0; tt < 2; tt++)
#pragma unroll
            for (int kk = 0; kk < 3; kk++) {
                int t = 2 * tp + tt;
                int fid = (((l1 * 2 + d) * 2 + half) * 4 + t) * 3 + kk;
                uint4 v = gw4[2048 + fid * 64 + lane];
                afr[SL(l1 + 1, tt, kk)] = park_frag(v);
            }
#pragma unroll
    for (int kk = 0; kk < 2; kk++) {
        uint4 v = gw4[14336 + kk * 64 + lane];
        afr[SWL(kk)] = park_frag(v);
    }

    // ---- L0 input-weight columns (K=3) in registers: Wc[tt][g*3+k] ------
    float WcA[12], WcB[12];
    {
        int uA = half * 16 + q * 4 + 2 * tp;
#pragma unroll
        for (int g = 0; g < 4; g++)
#pragma unroll
            for (int k = 0; k < 3; k++) {
                WcA[g * 3 + k] = Wih0g[(d * 128 + g * 32 + uA) * 3 + k];
                WcB[g * 3 + k] = Wih0g[(d * 128 + g * 32 + uA + 1) * 3 + k];
            }
    }

    // ---- biases (VGPRs), c-state, h-init into PARITY-1 regions ----------
    f32x4 bias[5][2];
    float cs[5][2];
    {
        unsigned short* zh1 = (unsigned short*)(zb + 2880);   // parity 1
#pragma unroll
        for (int l = 0; l < 5; l++)
#pragma unroll
            for (int tt = 0; tt < 2; tt++) {
                int unit = half * 16 + q * 4 + (2 * tp + tt); // q-major remap
                bias[l][tt] = *(const f32x4*)(biasf + ((l * 2 + d) * 32 + unit) * 4);
                int idx = ((2 * l + d) * BATCH + row) * 32 + unit;
                cs[l][tt] = c0[idx];
                zh1[l * 1152 + n * 72 + d * 32 + unit] = f2h_bits(h0[idx]);
            }
    }
    const float bl0 = blinf[0], bl1 = blinf[1], bl2 = blinf[2];
    float y0 = startf[0], y1 = startf[1], y2 = startf[2];
    __syncthreads();

#define LOADAT(BASE, L, DD) \
    __builtin_bit_cast(half8, *(const uint4*)&(BASE)[(L) * 576 + n * 36 + (DD) * 16 + q * 4])
#define STPACK(ZH, L, P) \
    *(unsigned*)((ZH) + (L) * 1152 + n * 72 + d * 32 + half * 16 + q * 4 + 2 * tp) = (P);
#define ACT_STORE(ZH, L, A0, A1, CSL)                                   \
    {                                                                    \
        f32x4 a2[2] = {(A0), (A1)};                                      \
        unsigned short hb[2];                                            \
        _Pragma("unroll")                                                \
        for (int tt = 0; tt < 2; tt++) {                                 \
            float ii = sigm(a2[tt][0]), ff = sigm(a2[tt][1]);            \
            float gg = tanhx(a2[tt][2]), oo = sigm(a2[tt][3]);           \
            (CSL)[tt] = ff * (CSL)[tt] + ii * gg;                        \
            hb[tt] = f2h_bits(oo * tanhx((CSL)[tt]));                    \
        }                                                                \
        STPACK(ZH, L, (unsigned)hb[0] | ((unsigned)hb[1] << 16));        \
    }

    const f32x4 fz = (f32x4){0.f, 0.f, 0.f, 0.f};

    // accn pipeline: next-layer recurrent MFMA result, crosses barriers
    f32x4 accnA, accnB;
    {
        half8 bh0i = LOADAT(zb + 2880, 0, d);     // parity-1 region 0 = h(-1)
        accnA = MFMA(afr[SL0R(0)], bh0i, bias[0][0]);
        accnB = MFMA(afr[SL0R(1)], bh0i, bias[0][1]);
    }

    for (int ts = 0; ts < T_STEPS; ts++) {
        const int p = ts & 1;
        unsigned* zbp = zb + p * 2880;            // current-parity regions
        unsigned* zbq = zb + (p ^ 1) * 2880;      // previous-parity regions
        unsigned short* zhp = (unsigned short*)zbp;

        // ---------- SEG0: layer 0 (no pre-barrier; y + accn in regs) -----
        {
            half8 nb2 = LOADAT(zbq, 1, d);        // h1(ts-1): prefetch early
            f32x4 acc0 = accnA, acc1 = accnB;
#pragma unroll
            for (int g = 0; g < 4; g++) {         // W_ih0 (K=3) on the VALU
                acc0[g] = __builtin_fmaf(WcA[g * 3 + 0], y0,
                          __builtin_fmaf(WcA[g * 3 + 1], y1,
                          __builtin_fmaf(WcA[g * 3 + 2], y2, acc0[g])));
                acc1[g] = __builtin_fmaf(WcB[g * 3 + 0], y0,
                          __builtin_fmaf(WcB[g * 3 + 1], y1,
                          __builtin_fmaf(WcB[g * 3 + 2], y2, acc1[g])));
            }
            accnA = MFMA(afr[SL(1, 0, 2)], nb2, bias[1][0]);   // L1 recurrent
            accnB = MFMA(afr[SL(1, 1, 2)], nb2, bias[1][1]);
            ACT_STORE(zhp, 0, acc0, acc1, cs[0]);
            __syncthreads();                                   // B1
        }

        // ---------- SEG 1..3 (split-K: parallel MFMAs, add at end) -------
#pragma unroll
        for (int l = 1; l <= 3; l++) {
            half8 b0 = LOADAT(zbp, l - 1, 0);
            half8 b1 = LOADAT(zbp, l - 1, 1);
            half8 nb2 = LOADAT(zbq, l + 1, d);    // h_{l+1}(ts-1)
            f32x4 acc0 = MFMA(afr[SL(l, 0, 0)], b0, accnA);
            f32x4 acc0b = MFMA(afr[SL(l, 0, 1)], b1, fz);
            f32x4 acc1 = MFMA(afr[SL(l, 1, 0)], b0, accnB);
            f32x4 acc1b = MFMA(afr[SL(l, 1, 1)], b1, fz);
            accnA = MFMA(afr[SL(l + 1, 0, 2)], nb2, bias[l + 1][0]);
            accnB = MFMA(afr[SL(l + 1, 1, 2)], nb2, bias[l + 1][1]);
            acc0 += acc0b;
            acc1 += acc1b;
            ACT_STORE(zhp, l, acc0, acc1, cs[l]);
            __syncthreads();                                   // B2..B4
        }

        // ---------- SEG4 --------------------------------------------------
        {
            half8 b0 = LOADAT(zbp, 3, 0);
            half8 b1 = LOADAT(zbp, 3, 1);
            half8 nbh0 = LOADAT(zbp, 0, d);       // h0(ts), produced pre-B1
            f32x4 acc0 = MFMA(afr[SL(4, 0, 0)], b0, accnA);
            f32x4 acc0b = MFMA(afr[SL(4, 0, 1)], b1, fz);
            f32x4 acc1 = MFMA(afr[SL(4, 1, 0)], b0, accnB);
            f32x4 acc1b = MFMA(afr[SL(4, 1, 1)], b1, fz);
            accnA = MFMA(afr[SL0R(0)], nbh0, bias[0][0]);      // L0 rec, ts+1
            accnB = MFMA(afr[SL0R(1)], nbh0, bias[0][1]);
            acc0 += acc0b;
            acc1 += acc1b;
            ACT_STORE(zhp, 4, acc0, acc1, cs[4]);
            __syncthreads();                                   // B5
        }

        // ---------- Y: all waves; replicated Wlin -> y on ALL lanes ------
        {
            half8 c0f = LOADAT(zbp, 4, 0);
            half8 c1f = LOADAT(zbp, 4, 1);
            f32x4 acc  = MFMA(afr[SWL(0)], c0f, fz);
            f32x4 accb = MFMA(afr[SWL(1)], c1f, fz);
            y0 = tanhx(acc[0] + accb[0] + bl0);   // valid on every lane
            y1 = tanhx(acc[1] + accb[1] + bl1);
            y2 = tanhx(acc[2] + accb[2] + bl2);
            if (w == 0 && q == 0) {
                float* op = out + (ts * BATCH + row) * 3;
                op[0] = y0; op[1] = y1; op[2] = y2;
            }
        }
        // no barrier: Y reads region[p][4]; next write to it is SEG4@(ts+2).
    }
#undef LOADAT
#undef STPACK
#undef ACT_STORE
}

extern "C" void kernel_launch(void* const* d_in, const int* in_sizes, int n_in,
                              void* d_out, int out_size, void* d_ws, size_t ws_size,
                              hipStream_t stream)
{
    const float* h0   = (const float*)d_in[0];
    const float* c0   = (const float*)d_in[1];
    const float* stok = (const float*)d_in[2];
    const float* Wih0 = (const float*)d_in[3];
    const float* Whh0 = (const float*)d_in[4];
    const float* bih0 = (const float*)d_in[5];
    const float* bhh0 = (const float*)d_in[6];
    const float* Wih  = (const float*)d_in[7];
    const float* Whh  = (const float*)d_in[8];
    const float* bih  = (const float*)d_in[9];
    const float* bhh  = (const float*)d_in[10];
    const float* Wlin = (const float*)d_in[11];
    const float* blin = (const float*)d_in[12];

    prep_kernel<<<458, 256, 0, stream>>>(Wih0, Whh0, bih0, bhh0, Wih, Whh,
                                         bih, bhh, Wlin, blin, stok, (char*)d_ws);
    lstm_kernel<<<64, 512, 0, stream>>>((const char*)d_ws, h0, c0, Wih0,
                                        (float*)d_out);
}

// Round 7
// 628.873 us; speedup vs baseline: 1.5576x; 1.0258x over previous
//
#include <hip/hip_runtime.h>
#include <hip/hip_fp16.h>

// ---------------------------------------------------------------------------
// Bidirectional 5-layer LSTM decoder, B=1024, H=32, T=200, feedback y->x.
// Round 21 = r20 (8 waves 2/SIMD, parity regions, recurrent hoist, L0
// VALU-ized, replicated Wlin, rcp-sigm, Pade-tanh, split-K MFMA) with the 5
// in-loop __syncthreads replaced by a RAW LDS-only barrier:
//   __syncthreads lowers to "s_waitcnt vmcnt(0) expcnt(0) lgkmcnt(0);
//   s_barrier". The Y-phase global store of `out` therefore forced wave 0 to
//   drain a ~300-900 cyc HBM store-ack at the NEXT barrier every ts, with
//   all 7 other waves waiting behind it. In-loop inter-wave communication is
//   LDS-only, so the correct minimal barrier is:
//      s_waitcnt lgkmcnt(0)  (drain ds_writes; memory-clobber ordered)
//      s_barrier             (raw builtin: no implicit vmcnt drain)
//      compiler fences (sched_barrier(0) + ""::"memory") on both sides.
//   The out-store becomes fire-and-forget; kernel-end drain covers it.
// r18 lesson: s_barrier < LDS polling. r15: keep 2 waves/SIMD. r20 lesson:
// chain latency is the currency (~3-6 cyc per removed chain instr).
// Race audit identical to r19/r20 (barrier-ordered; parity regions give WAR
// slack; SEG4 reads region[p][0] produced pre-B1; Y reads region[p][4]
// post-B5, next writer SEG4@(ts+2)).
// ---------------------------------------------------------------------------

#define T_STEPS 200
#define BATCH 1024

#define BIAS_OFF_B  231424            // 1280 floats [l*2+d][u][g]
#define BLIN_OFF_B  236544            // 3 floats
#define START_OFF_B 236556            // 3 floats

typedef _Float16 half8 __attribute__((ext_vector_type(8)));
typedef float f32x4 __attribute__((ext_vector_type(4)));
typedef unsigned u32x4 __attribute__((ext_vector_type(4)));

__global__ __launch_bounds__(256) void prep_kernel(
    const float* __restrict__ Wih0, const float* __restrict__ Whh0,
    const float* __restrict__ bih0, const float* __restrict__ bhh0,
    const float* __restrict__ Wih,  const float* __restrict__ Whh,
    const float* __restrict__ bih,  const float* __restrict__ bhh,
    const float* __restrict__ Wlin, const float* __restrict__ blin,
    const float* __restrict__ stok, char* __restrict__ ws)
{
    int i = blockIdx.x * 256 + threadIdx.x;
    _Float16* Wo = (_Float16*)ws;
    float* biasf  = (float*)(ws + BIAS_OFF_B);
    float* blinf  = (float*)(ws + BLIN_OFF_B);
    float* startf = (float*)(ws + START_OFF_B);

    if (i < 16384) {                       // layer-0 A-frags
        int fid = i >> 9, r = i & 511;
        int lane = r >> 3, j = r & 7, q = lane >> 4, m = lane & 15;
        int kk = fid & 1, t = (fid >> 1) & 3, half = (fid >> 3) & 1, d = fid >> 4;
        int k = kk * 32 + q * 8 + j;
        int unit = half * 16 + (m >> 2) * 4 + t;   // q-major, t-minor
        int gr = (m & 3) * 32 + unit;      // torch gate order i,f,g,o
        float v = 0.f;
        if (k < 3)       v = Wih0[(d * 128 + gr) * 3 + k];
        else if (k >= 32) v = Whh0[(d * 128 + gr) * 32 + (k - 32)];
        Wo[i] = (_Float16)v;
    } else if (i < 114688) {               // layers 1-4 A-frags
        int e = i - 16384;
        int fid = e >> 9, r = e & 511;
        int lane = r >> 3, j = r & 7, q = lane >> 4, m = lane & 15;
        int kk = fid % 3, t = (fid / 3) & 3, half = (fid / 12) & 1;
        int d = (fid / 24) & 1, l1 = fid / 48;
        int k = kk * 32 + q * 8 + j;
        int unit = half * 16 + (m >> 2) * 4 + t;   // q-major, t-minor
        int gr = (m & 3) * 32 + unit;
        float v;
        if (k < 64) v = Wih[((l1 * 2 + d) * 128 + gr) * 64 + k];
        else        v = Whh[((l1 * 2 + d) * 128 + gr) * 32 + (k - 64)];
        Wo[i] = (_Float16)v;
    } else if (i < 115712) {               // Wlin A-frags, rows REPLICATED %4
        int e = i - 114688;
        int fid = e >> 9, r = e & 511;
        int lane = r >> 3, j = r & 7, q = lane >> 4, m = lane & 15;
        int k = fid * 32 + q * 8 + j;
        int mr = m & 3;                    // row m holds Wlin[m&3] (row3 = 0)
        Wo[i] = (_Float16)((mr < 3) ? Wlin[mr * 64 + k] : 0.f);
    } else if (i < 115712 + 1280) {        // fused biases [l*2+d][u][g]
        int b = i - 115712;
        int ld = b / 128, rem = b % 128;
        int u = rem / 4, g = rem % 4;
        int gr = g * 32 + u;
        float v;
        if (ld < 2) v = bih0[ld * 128 + gr] + bhh0[ld * 128 + gr];
        else        v = bih[(ld - 2) * 128 + gr] + bhh[(ld - 2) * 128 + gr];
        biasf[b] = v;
    } else if (i < 115712 + 1280 + 3) {
        blinf[i - (115712 + 1280)] = blin[i - (115712 + 1280)];
    } else if (i < 115712 + 1280 + 6) {
        startf[i - (115712 + 1280 + 3)] = stok[i - (115712 + 1280 + 3)];
    }
}

// fast sigmoid: exp2-based exp + RAW v_rcp_f32 (no exact-div expansion)
__device__ __forceinline__ float sigm(float x) {
    return __builtin_amdgcn_rcpf(1.f + __expf(-x));
}
// tanh via Pade(7,6), input clamped to +-4 (abs err <= ~7e-4)
__device__ __forceinline__ float tanhx(float x) {
    float xc = fminf(fmaxf(x, -4.0f), 4.0f);
    float u  = xc * xc;
    float p  = __builtin_fmaf(__builtin_fmaf(u + 378.0f, u, 17325.0f), u, 135135.0f);
    float qd = __builtin_fmaf(__builtin_fmaf(__builtin_fmaf(u, 28.0f, 3150.0f), u, 62370.0f), u, 135135.0f);
    return xc * p * __builtin_amdgcn_rcpf(qd);
}
__device__ __forceinline__ unsigned short f2h_bits(float x) {
    return __builtin_bit_cast(unsigned short, (_Float16)x);
}

// Park a 16B fragment into a contiguous AGPR quad (r17-proven).
__device__ __forceinline__ half8 park_frag(uint4 v) {
    u32x4 t; t[0] = v.x; t[1] = v.y; t[2] = v.z; t[3] = v.w;
    u32x4 r;
    __asm__("" : "=a"(r) : "0"(t));
    return __builtin_bit_cast(half8, r);
}

// RAW LDS-only barrier: drains ds ops (lgkmcnt) but NOT global stores
// (vmcnt). HK pattern: asm waitcnt w/ memory clobber + sched_barrier fences
// around the raw s_barrier builtin. Safe because all inter-wave data flow in
// the loop is LDS; the only global op is the out-store nobody reads.
__device__ __forceinline__ void bar_lds() {
    __asm__ volatile("s_waitcnt lgkmcnt(0)" ::: "memory");
    __builtin_amdgcn_sched_barrier(0);
    __builtin_amdgcn_s_barrier();
    __builtin_amdgcn_sched_barrier(0);
    __asm__ volatile("" ::: "memory");
}

#define MFMA(A, B, C) __builtin_amdgcn_mfma_f32_16x16x32_f16((A), (B), (C), 0, 0, 0)

// per-wave frag slots (28 frags = 112 AGPR)
#define SL0R(tt)       (tt)                                     // 0..1  (Whh0)
#define SL(l, tt, kk)  (2 + (((l) - 1) * 2 + (tt)) * 3 + (kk))  // 2..25
#define SWL(kk)        (26 + (kk))                              // 26,27

__global__ __launch_bounds__(512, 2) void lstm_kernel(
    const char* __restrict__ ws,
    const float* __restrict__ h0,
    const float* __restrict__ c0,
    const float* __restrict__ Wih0g,
    float* __restrict__ out)
{
    const int tid  = threadIdx.x;
    const int w    = tid >> 6;
    const int d    = w & 1;           // direction
    const int half = (w >> 1) & 1;    // unit half
    const int tp   = w >> 2;          // t-pair (t = 2*tp + tt)
    const int lane = tid & 63;
    const int q    = lane >> 4;       // quad
    const int n    = lane & 15;       // batch row within block
    const int row  = blockIdx.x * 16 + n;

    // parity-doubled regions: [2][5][16 rows][36 words]
    __shared__ unsigned zb[5760];

    const uint4* gw4 = (const uint4*)ws;
    const float* biasf  = (const float*)(ws + BIAS_OFF_B);
    const float* blinf  = (const float*)(ws + BLIN_OFF_B);
    const float* startf = (const float*)(ws + START_OFF_B);

    for (int i = tid; i < 5760; i += 512) zb[i] = 0;
    __syncthreads();

    // ---- park this wave's A-fragments in AGPRs (28 frags = 112 AGPR) ----
    half8 afr[28];
#pragma unroll
    for (int tt = 0; tt < 2; tt++) {      // L0: only the Whh0 (kk=1) frag
        int t = 2 * tp + tt;
        uint4 v = gw4[((((d * 2 + half) * 4 + t) * 2) + 1) * 64 + lane];
        afr[SL0R(tt)] = park_frag(v);
    }
#pragma unroll
    for (int l1 = 0; l1 < 4; l1++)
#pragma unroll
        for (int tt = 0; tt < 2; tt++)
#pragma unroll
            for (int kk = 0; kk < 3; kk++) {
                int t = 2 * tp + tt;
                int fid = (((l1 * 2 + d) * 2 + half) * 4 + t) * 3 + kk;
                uint4 v = gw4[2048 + fid * 64 + lane];
                afr[SL(l1 + 1, tt, kk)] = park_frag(v);
            }
#pragma unroll
    for (int kk = 0; kk < 2; kk++) {
        uint4 v = gw4[14336 + kk * 64 + lane];
        afr[SWL(kk)] = park_frag(v);
    }

    // ---- L0 input-weight columns (K=3) in registers: Wc[tt][g*3+k] ------
    float WcA[12], WcB[12];
    {
        int uA = half * 16 + q * 4 + 2 * tp;
#pragma unroll
        for (int g = 0; g < 4; g++)
#pragma unroll
            for (int k = 0; k < 3; k++) {
                WcA[g * 3 + k] = Wih0g[(d * 128 + g * 32 + uA) * 3 + k];
                WcB[g * 3 + k] = Wih0g[(d * 128 + g * 32 + uA + 1) * 3 + k];
            }
    }

    // ---- biases (VGPRs), c-state, h-init into PARITY-1 regions ----------
    f32x4 bias[5][2];
    float cs[5][2];
    {
        unsigned short* zh1 = (unsigned short*)(zb + 2880);   // parity 1
#pragma unroll
        for (int l = 0; l < 5; l++)
#pragma unroll
            for (int tt = 0; tt < 2; tt++) {
                int unit = half * 16 + q * 4 + (2 * tp + tt); // q-major remap
                bias[l][tt] = *(const f32x4*)(biasf + ((l * 2 + d) * 32 + unit) * 4);
                int idx = ((2 * l + d) * BATCH + row) * 32 + unit;
                cs[l][tt] = c0[idx];
                zh1[l * 1152 + n * 72 + d * 32 + unit] = f2h_bits(h0[idx]);
            }
    }
    const float bl0 = blinf[0], bl1 = blinf[1], bl2 = blinf[2];
    float y0 = startf[0], y1 = startf[1], y2 = startf[2];
    __syncthreads();

#define LOADAT(BASE, L, DD) \
    __builtin_bit_cast(half8, *(const uint4*)&(BASE)[(L) * 576 + n * 36 + (DD) * 16 + q * 4])
#define STPACK(ZH, L, P) \
    *(unsigned*)((ZH) + (L) * 1152 + n * 72 + d * 32 + half * 16 + q * 4 + 2 * tp) = (P);
#define ACT_STORE(ZH, L, A0, A1, CSL)                                   \
    {                                                                    \
        f32x4 a2[2] = {(A0), (A1)};                                      \
        unsigned short hb[2];                                            \
        _Pragma("unroll")                                                \
        for (int tt = 0; tt < 2; tt++) {                                 \
            float ii = sigm(a2[tt][0]), ff = sigm(a2[tt][1]);            \
            float gg = tanhx(a2[tt][2]), oo = sigm(a2[tt][3]);           \
            (CSL)[tt] = ff * (CSL)[tt] + ii * gg;                        \
            hb[tt] = f2h_bits(oo * tanhx((CSL)[tt]));                    \
        }                                                                \
        STPACK(ZH, L, (unsigned)hb[0] | ((unsigned)hb[1] << 16));        \
    }

    const f32x4 fz = (f32x4){0.f, 0.f, 0.f, 0.f};

    // accn pipeline: next-layer recurrent MFMA result, crosses barriers
    f32x4 accnA, accnB;
    {
        half8 bh0i = LOADAT(zb + 2880, 0, d);     // parity-1 region 0 = h(-1)
        accnA = MFMA(afr[SL0R(0)], bh0i, bias[0][0]);
        accnB = MFMA(afr[SL0R(1)], bh0i, bias[0][1]);
    }

    for (int ts = 0; ts < T_STEPS; ts++) {
        const int p = ts & 1;
        unsigned* zbp = zb + p * 2880;            // current-parity regions
        unsigned* zbq = zb + (p ^ 1) * 2880;      // previous-parity regions
        unsigned short* zhp = (unsigned short*)zbp;

        // ---------- SEG0: layer 0 (no pre-barrier; y + accn in regs) -----
        {
            half8 nb2 = LOADAT(zbq, 1, d);        // h1(ts-1): prefetch early
            f32x4 acc0 = accnA, acc1 = accnB;
#pragma unroll
            for (int g = 0; g < 4; g++) {         // W_ih0 (K=3) on the VALU
                acc0[g] = __builtin_fmaf(WcA[g * 3 + 0], y0,
                          __builtin_fmaf(WcA[g * 3 + 1], y1,
                          __builtin_fmaf(WcA[g * 3 + 2], y2, acc0[g])));
                acc1[g] = __builtin_fmaf(WcB[g * 3 + 0], y0,
                          __builtin_fmaf(WcB[g * 3 + 1], y1,
                          __builtin_fmaf(WcB[g * 3 + 2], y2, acc1[g])));
            }
            accnA = MFMA(afr[SL(1, 0, 2)], nb2, bias[1][0]);   // L1 recurrent
            accnB = MFMA(afr[SL(1, 1, 2)], nb2, bias[1][1]);
            ACT_STORE(zhp, 0, acc0, acc1, cs[0]);
            bar_lds();                                         // B1
        }

        // ---------- SEG 1..3 (split-K: parallel MFMAs, add at end) -------
#pragma unroll
        for (int l = 1; l <= 3; l++) {
            half8 b0 = LOADAT(zbp, l - 1, 0);
            half8 b1 = LOADAT(zbp, l - 1, 1);
            half8 nb2 = LOADAT(zbq, l + 1, d);    // h_{l+1}(ts-1)
            f32x4 acc0 = MFMA(afr[SL(l, 0, 0)], b0, accnA);
            f32x4 acc0b = MFMA(afr[SL(l, 0, 1)], b1, fz);
            f32x4 acc1 = MFMA(afr[SL(l, 1, 0)], b0, accnB);
            f32x4 acc1b = MFMA(afr[SL(l, 1, 1)], b1, fz);
            accnA = MFMA(afr[SL(l + 1, 0, 2)], nb2, bias[l + 1][0]);
            accnB = MFMA(afr[SL(l + 1, 1, 2)], nb2, bias[l + 1][1]);
            acc0 += acc0b;
            acc1 += acc1b;
            ACT_STORE(zhp, l, acc0, acc1, cs[l]);
            bar_lds();                                         // B2..B4
        }

        // ---------- SEG4 --------------------------------------------------
        {
            half8 b0 = LOADAT(zbp, 3, 0);
            half8 b1 = LOADAT(zbp, 3, 1);
            half8 nbh0 = LOADAT(zbp, 0, d);       // h0(ts), produced pre-B1
            f32x4 acc0 = MFMA(afr[SL(4, 0, 0)], b0, accnA);
            f32x4 acc0b = MFMA(afr[SL(4, 0, 1)], b1, fz);
            f32x4 acc1 = MFMA(afr[SL(4, 1, 0)], b0, accnB);
            f32x4 acc1b = MFMA(afr[SL(4, 1, 1)], b1, fz);
            accnA = MFMA(afr[SL0R(0)], nbh0, bias[0][0]);      // L0 rec, ts+1
            accnB = MFMA(afr[SL0R(1)], nbh0, bias[0][1]);
            acc0 += acc0b;
            acc1 += acc1b;
            ACT_STORE(zhp, 4, acc0, acc1, cs[4]);
            bar_lds();                                         // B5
        }

        // ---------- Y: all waves; replicated Wlin -> y on ALL lanes ------
        {
            half8 c0f = LOADAT(zbp, 4, 0);
            half8 c1f = LOADAT(zbp, 4, 1);
            f32x4 acc  = MFMA(afr[SWL(0)], c0f, fz);
            f32x4 accb = MFMA(afr[SWL(1)], c1f, fz);
            y0 = tanhx(acc[0] + accb[0] + bl0);   // valid on every lane
            y1 = tanhx(acc[1] + accb[1] + bl1);
            y2 = tanhx(acc[2] + accb[2] + bl2);
            if (w == 0 && q == 0) {
                float* op = out + (ts * BATCH + row) * 3;
                op[0] = y0; op[1] = y1; op[2] = y2;   // fire-and-forget now
            }
        }
        // no barrier: Y reads region[p][4]; next write to it is SEG4@(ts+2).
    }
#undef LOADAT
#undef STPACK
#undef ACT_STORE
}

extern "C" void kernel_launch(void* const* d_in, const int* in_sizes, int n_in,
                              void* d_out, int out_size, void* d_ws, size_t ws_size,
                              hipStream_t stream)
{
    const float* h0   = (const float*)d_in[0];
    const float* c0   = (const float*)d_in[1];
    const float* stok = (const float*)d_in[2];
    const float* Wih0 = (const float*)d_in[3];
    const float* Whh0 = (const float*)d_in[4];
    const float* bih0 = (const float*)d_in[5];
    const float* bhh0 = (const float*)d_in[6];
    const float* Wih  = (const float*)d_in[7];
    const float* Whh  = (const float*)d_in[8];
    const float* bih  = (const float*)d_in[9];
    const float* bhh  = (const float*)d_in[10];
    const float* Wlin = (const float*)d_in[11];
    const float* blin = (const float*)d_in[12];

    prep_kernel<<<458, 256, 0, stream>>>(Wih0, Whh0, bih0, bhh0, Wih, Whh,
                                         bih, bhh, Wlin, blin, stok, (char*)d_ws);
    lstm_kernel<<<64, 512, 0, stream>>>((const char*)d_ws, h0, c0, Wih0,
                                        (float*)d_out);
}